// Round 1
// baseline (31.704 us; speedup 1.0000x reference)
//
#include <hip/hip_runtime.h>

#define N2 128
#define BLOCK 256

__global__ __launch_bounds__(BLOCK) void matcher_kernel(
    const float4* __restrict__ boxes1,
    const float4* __restrict__ boxes2,
    float* __restrict__ out_vals,
    float* __restrict__ out_idx,
    float* __restrict__ out_labels,
    int n1)
{
#pragma clang fp contract(off)
    __shared__ float4 s_b2[N2];
    __shared__ float s_area2[N2];

    const int t = threadIdx.x;
    if (t < N2) {
        float4 b = boxes2[t];           // (y1, x1, y2, x2)
        s_b2[t] = b;
        s_area2[t] = (b.z - b.x) * (b.w - b.y);
    }
    __syncthreads();

    const int i = blockIdx.x * BLOCK + t;
    if (i >= n1) return;

    const float4 a = boxes1[i];         // (y1, x1, y2, x2)
    const float area1 = (a.z - a.x) * (a.w - a.y);

    float best = -1.0f;                 // any IoU (>=0) beats this at j=0
    int bidx = 0;

#pragma unroll 4
    for (int j = 0; j < N2; ++j) {
        const float4 b = s_b2[j];
        const float iy1 = fmaxf(a.x, b.x);
        const float ix1 = fmaxf(a.y, b.y);
        const float iy2 = fminf(a.z, b.z);
        const float ix2 = fminf(a.w, b.w);
        const float hy = fmaxf(iy2 - iy1, 0.0f);
        const float hx = fmaxf(ix2 - ix1, 0.0f);
        const float inter = hy * hx;
        // replicate reference op order exactly: (area1 + area2) - inter
        const float uni = (area1 + s_area2[j]) - inter;
        const float iou = inter / fmaxf(uni, 1e-10f);
        if (iou > best) { best = iou; bidx = j; }   // strict > == first-max argmax
    }

    out_vals[i]   = best;
    out_idx[i]    = (float)bidx;
    out_labels[i] = (best >= 0.7f) ? 1.0f : ((best < 0.3f) ? 0.0f : -1.0f);
}

extern "C" void kernel_launch(void* const* d_in, const int* in_sizes, int n_in,
                              void* d_out, int out_size, void* d_ws, size_t ws_size,
                              hipStream_t stream) {
    const float4* boxes1 = (const float4*)d_in[0];
    const float4* boxes2 = (const float4*)d_in[1];
    const int n1 = in_sizes[0] / 4;     // 262144 boxes, 4 floats each

    float* out = (float*)d_out;
    float* out_vals   = out;
    float* out_idx    = out + n1;
    float* out_labels = out + 2 * n1;

    const int grid = (n1 + BLOCK - 1) / BLOCK;
    matcher_kernel<<<grid, BLOCK, 0, stream>>>(boxes1, boxes2,
                                               out_vals, out_idx, out_labels, n1);
}